// Round 1
// baseline (49.381 us; speedup 1.0000x reference)
//
#include <hip/hip_runtime.h>
#include <hip/hip_bf16.h>

#define H 2048
#define RIN 2304
#define SW 256
#define SD 200

// ws layout (floats):
//  [0..3)    cdot (3 used)
//  [4..260)  sdot (256)
//  [260..6404)   gh0 (6144)
//  [6404..12548) gh1 (6144)
//  [12548..18692) gi0_emb (6144)
#define WS_CDOT 0
#define WS_SDOT 4
#define WS_GH0  260
#define WS_GH1  6404
#define WS_GI0  12548

// out layout (floats): [0..100) logits, [100..2148) h0, [2148..4196) h1,
// [4196..55396) new_stack (200x256)

__device__ __forceinline__ float wave_dot(const float* __restrict__ w,
                                          const float* __restrict__ x, int K) {
  int lane = threadIdx.x & 63;
  const float4* w4 = (const float4*)w;
  const float4* x4 = (const float4*)x;
  int n4 = K >> 2;
  float acc = 0.f;
  for (int i = lane; i < n4; i += 64) {
    float4 a = w4[i];
    float4 b = x4[i];
    acc += a.x * b.x + a.y * b.y + a.z * b.z + a.w * b.w;
  }
  #pragma unroll
  for (int off = 32; off > 0; off >>= 1) acc += __shfl_down(acc, off);
  return acc;  // valid in lane 0
}

__device__ __forceinline__ float sigmoidf(float x) {
  return 1.f / (1.f + expf(-x));
}

// K1: all input-only matvecs. wave-per-row.
// waves: [0,6144) gh0 = Whh0@h0+bhh0 ; [6144,12288) gh1 = Whh1@h1+bhh1 ;
// [12288,18432) gi0 = Wih0[:, :2048]@emb_row + bih0 ;
// [18432,18435) cdot = Wc@h2s+bc ; [18435,18691) sdot = Ws@h2s+bs
__global__ void k1_matvecs(const float* __restrict__ hidden, const int* __restrict__ inp,
                           const float* __restrict__ emb,
                           const float* __restrict__ Wc, const float* __restrict__ bc,
                           const float* __restrict__ Ws, const float* __restrict__ bs,
                           const float* __restrict__ Wih0, const float* __restrict__ bih0,
                           const float* __restrict__ Whh0, const float* __restrict__ bhh0,
                           const float* __restrict__ Whh1, const float* __restrict__ bhh1,
                           float* __restrict__ ws) {
  int w = blockIdx.x * 4 + (threadIdx.x >> 6);
  int lane = threadIdx.x & 63;
  if (w < 6144) {
    float d = wave_dot(Whh0 + (size_t)w * H, hidden, H);
    if (lane == 0) ws[WS_GH0 + w] = d + bhh0[w];
  } else if (w < 12288) {
    int r = w - 6144;
    float d = wave_dot(Whh1 + (size_t)r * H, hidden + H, H);
    if (lane == 0) ws[WS_GH1 + r] = d + bhh1[r];
  } else if (w < 18432) {
    int r = w - 12288;
    const float* erow = emb + (size_t)inp[0] * H;
    float d = wave_dot(Wih0 + (size_t)r * RIN, erow, H);  // first 2048 cols
    if (lane == 0) ws[WS_GI0 + r] = d + bih0[r];
  } else if (w < 18435) {
    int r = w - 18432;
    float d = wave_dot(Wc + (size_t)r * (2 * H), hidden, 2 * H);
    if (lane == 0) ws[WS_CDOT + r] = d + bc[r];
  } else if (w < 18691) {
    int r = w - 18435;
    float d = wave_dot(Ws + (size_t)r * (2 * H), hidden, 2 * H);
    if (lane == 0) ws[WS_SDOT + r] = d + bs[r];
  }
}

// K2: blocks [0,2048): GRU layer0 finish (one j per block; 3 waves do the
//     K=256 stack-column dots of Wih0); blocks [2048,2248): new_stack rows.
__global__ void k2_stack_gru0(const float* __restrict__ stack,
                              const float* __restrict__ hidden,
                              const float* __restrict__ Wih0,
                              const float* __restrict__ ws,
                              float* out) {
  int t = threadIdx.x;
  // redundant per-thread softmax of the 3 control logits (cheap, L2-hot)
  float c0 = ws[WS_CDOT + 0], c1 = ws[WS_CDOT + 1], c2 = ws[WS_CDOT + 2];
  float m = fmaxf(c0, fmaxf(c1, c2));
  float e0 = expf(c0 - m), e1 = expf(c1 - m), e2 = expf(c2 - m);
  float inv = 1.f / (e0 + e1 + e2);
  float a_push = e0 * inv, a_pop = e1 * inv, a_noop = e2 * inv;

  int b = blockIdx.x;
  if (b >= 2048) {
    int r = b - 2048;
    float up = (r == 0) ? tanhf(ws[WS_SDOT + t]) : stack[(r - 1) * SW + t];
    float down = (r == SD - 1) ? 0.f : stack[(r + 1) * SW + t];
    out[4196 + r * SW + t] = a_noop * stack[r * SW + t] + a_push * up + a_pop * down;
    return;
  }
  __shared__ float st[SW];
  __shared__ float gred[3];
  // stacktop = new_stack row 0
  st[t] = a_noop * stack[t] + a_push * tanhf(ws[WS_SDOT + t]) + a_pop * stack[SW + t];
  __syncthreads();
  int wv = t >> 6, lane = t & 63;
  int j = b;
  if (wv < 3) {
    const float4* w4 = (const float4*)(Wih0 + (size_t)(wv * H + j) * RIN + H);
    const float4* s4 = (const float4*)st;
    float4 a = w4[lane];
    float4 xv = s4[lane];
    float acc = a.x * xv.x + a.y * xv.y + a.z * xv.z + a.w * xv.w;
    #pragma unroll
    for (int off = 32; off > 0; off >>= 1) acc += __shfl_down(acc, off);
    if (lane == 0) gred[wv] = acc;
  }
  __syncthreads();
  if (t == 0) {
    float gr = ws[WS_GI0 + j] + gred[0] + ws[WS_GH0 + j];
    float gz = ws[WS_GI0 + H + j] + gred[1] + ws[WS_GH0 + H + j];
    float r = sigmoidf(gr);
    float z = sigmoidf(gz);
    float n = tanhf(ws[WS_GI0 + 2 * H + j] + gred[2] + r * ws[WS_GH0 + 2 * H + j]);
    out[100 + j] = (1.f - z) * n + z * hidden[j];
  }
}

// K3: GRU layer1, fused matvec + combine. One j per block, 3 waves (192 thr).
__global__ void k3_gru1(const float* __restrict__ hidden,
                        const float* __restrict__ Wih1, const float* __restrict__ bih1,
                        const float* __restrict__ ws,
                        float* out) {
  int j = blockIdx.x;
  int t = threadIdx.x, wv = t >> 6, lane = t & 63;
  const float* h0 = out + 100;  // written by k2
  __shared__ float gred[3];
  int row = wv * H + j;
  float d = wave_dot(Wih1 + (size_t)row * H, h0, H);
  if (lane == 0) gred[wv] = d + bih1[row];
  __syncthreads();
  if (t == 0) {
    float r = sigmoidf(gred[0] + ws[WS_GH1 + j]);
    float z = sigmoidf(gred[1] + ws[WS_GH1 + H + j]);
    float n = tanhf(gred[2] + r * ws[WS_GH1 + 2 * H + j]);
    out[100 + H + j] = (1.f - z) * n + z * hidden[H + j];
  }
}

// K4: logits = Wd @ h1 + bd. wave-per-row, 100 rows.
__global__ void k4_logits(const float* __restrict__ Wd, const float* __restrict__ bd,
                          float* out) {
  int w = blockIdx.x * 4 + (threadIdx.x >> 6);
  int lane = threadIdx.x & 63;
  if (w >= 100) return;
  const float* h1 = out + 100 + H;  // written by k3
  float d = wave_dot(Wd + (size_t)w * H, h1, H);
  if (lane == 0) out[w] = d + bd[w];
}

extern "C" void kernel_launch(void* const* d_in, const int* in_sizes, int n_in,
                              void* d_out, int out_size, void* d_ws, size_t ws_size,
                              hipStream_t stream) {
  const int*   inp    = (const int*)d_in[0];
  const float* hidden = (const float*)d_in[1];
  const float* stack  = (const float*)d_in[2];
  const float* emb    = (const float*)d_in[3];
  const float* Wc     = (const float*)d_in[4];
  const float* bc     = (const float*)d_in[5];
  const float* Ws     = (const float*)d_in[6];
  const float* bs     = (const float*)d_in[7];
  const float* Wih0   = (const float*)d_in[8];
  const float* Whh0   = (const float*)d_in[9];
  const float* bih0   = (const float*)d_in[10];
  const float* bhh0   = (const float*)d_in[11];
  const float* Wih1   = (const float*)d_in[12];
  const float* Whh1   = (const float*)d_in[13];
  const float* bih1   = (const float*)d_in[14];
  const float* bhh1   = (const float*)d_in[15];
  const float* Wd     = (const float*)d_in[16];
  const float* bd     = (const float*)d_in[17];
  float* ws  = (float*)d_ws;
  float* out = (float*)d_out;

  k1_matvecs<<<4673, 256, 0, stream>>>(hidden, inp, emb, Wc, bc, Ws, bs,
                                       Wih0, bih0, Whh0, bhh0, Whh1, bhh1, ws);
  k2_stack_gru0<<<2248, 256, 0, stream>>>(stack, hidden, Wih0, ws, out);
  k3_gru1<<<2048, 192, 0, stream>>>(hidden, Wih1, bih1, ws, out);
  k4_logits<<<25, 256, 0, stream>>>(Wd, bd, out);
}

// Round 2
// 44.487 us; speedup vs baseline: 1.1100x; 1.1100x over previous
//
#include <hip/hip_runtime.h>
#include <hip/hip_bf16.h>

#define H 2048
#define RIN 2304
#define SW 256
#define SD 200

// ws layout (floats):
#define WS_CDOT 0
#define WS_SDOT 4
#define WS_GH0  260
#define WS_GH1  6404
#define WS_GI0  12548

// out layout (floats): [0..100) logits, [100..2148) h0, [2148..4196) h1,
// [4196..55396) new_stack (200x256)

__device__ __forceinline__ float wave_reduce(float acc) {
  #pragma unroll
  for (int off = 32; off > 0; off >>= 1) acc += __shfl_down(acc, off);
  return acc;  // valid in lane 0
}

// Per-lane partial dot over 2048 elements, fully unrolled: 8 w-loads + 8
// x-loads issued before any use, so 16 loads/lane are in flight (vs 1-2 in
// the rolled loop -> latency-bound at 2.7 TB/s).
__device__ __forceinline__ float dot2048_part(const float* __restrict__ w,
                                              const float* __restrict__ x) {
  int lane = threadIdx.x & 63;
  const float4* w4 = (const float4*)w + lane;
  const float4* x4 = (const float4*)x + lane;
  float4 a0 = w4[0],   a1 = w4[64],  a2 = w4[128], a3 = w4[192];
  float4 a4 = w4[256], a5 = w4[320], a6 = w4[384], a7 = w4[448];
  float4 b0 = x4[0],   b1 = x4[64],  b2 = x4[128], b3 = x4[192];
  float4 b4 = x4[256], b5 = x4[320], b6 = x4[384], b7 = x4[448];
  float acc = a0.x * b0.x + a0.y * b0.y + a0.z * b0.z + a0.w * b0.w;
  acc += a1.x * b1.x + a1.y * b1.y + a1.z * b1.z + a1.w * b1.w;
  acc += a2.x * b2.x + a2.y * b2.y + a2.z * b2.z + a2.w * b2.w;
  acc += a3.x * b3.x + a3.y * b3.y + a3.z * b3.z + a3.w * b3.w;
  acc += a4.x * b4.x + a4.y * b4.y + a4.z * b4.z + a4.w * b4.w;
  acc += a5.x * b5.x + a5.y * b5.y + a5.z * b5.z + a5.w * b5.w;
  acc += a6.x * b6.x + a6.y * b6.y + a6.z * b6.z + a6.w * b6.w;
  acc += a7.x * b7.x + a7.y * b7.y + a7.z * b7.z + a7.w * b7.w;
  return acc;
}

__device__ __forceinline__ float sigmoidf(float x) {
  return 1.f / (1.f + expf(-x));
}

// K1: all input-only matvecs. wave-per-row.
__global__ __launch_bounds__(256)
void k1_matvecs(const float* __restrict__ hidden, const int* __restrict__ inp,
                const float* __restrict__ emb,
                const float* __restrict__ Wc, const float* __restrict__ bc,
                const float* __restrict__ Ws, const float* __restrict__ bs,
                const float* __restrict__ Wih0, const float* __restrict__ bih0,
                const float* __restrict__ Whh0, const float* __restrict__ bhh0,
                const float* __restrict__ Whh1, const float* __restrict__ bhh1,
                float* __restrict__ ws) {
  int w = blockIdx.x * 4 + (threadIdx.x >> 6);
  int lane = threadIdx.x & 63;
  if (w < 6144) {
    float d = wave_reduce(dot2048_part(Whh0 + (size_t)w * H, hidden));
    if (lane == 0) ws[WS_GH0 + w] = d + bhh0[w];
  } else if (w < 12288) {
    int r = w - 6144;
    float d = wave_reduce(dot2048_part(Whh1 + (size_t)r * H, hidden + H));
    if (lane == 0) ws[WS_GH1 + r] = d + bhh1[r];
  } else if (w < 18432) {
    int r = w - 12288;
    const float* erow = emb + (size_t)inp[0] * H;
    float d = wave_reduce(dot2048_part(Wih0 + (size_t)r * RIN, erow));
    if (lane == 0) ws[WS_GI0 + r] = d + bih0[r];
  } else if (w < 18435) {
    int r = w - 18432;
    const float* wr = Wc + (size_t)r * (2 * H);
    float d = wave_reduce(dot2048_part(wr, hidden) +
                          dot2048_part(wr + H, hidden + H));
    if (lane == 0) ws[WS_CDOT + r] = d + bc[r];
  } else if (w < 18691) {
    int r = w - 18435;
    const float* wr = Ws + (size_t)r * (2 * H);
    float d = wave_reduce(dot2048_part(wr, hidden) +
                          dot2048_part(wr + H, hidden + H));
    if (lane == 0) ws[WS_SDOT + r] = d + bs[r];
  }
}

// K2: blocks [0,2048): GRU layer0 finish (one j per block; 3 waves do the
//     K=256 stack-column dots of Wih0); blocks [2048,2248): new_stack rows.
__global__ __launch_bounds__(256)
void k2_stack_gru0(const float* __restrict__ stack,
                   const float* __restrict__ hidden,
                   const float* __restrict__ Wih0,
                   const float* __restrict__ ws,
                   float* out) {
  int t = threadIdx.x;
  float c0 = ws[WS_CDOT + 0], c1 = ws[WS_CDOT + 1], c2 = ws[WS_CDOT + 2];
  float m = fmaxf(c0, fmaxf(c1, c2));
  float e0 = expf(c0 - m), e1 = expf(c1 - m), e2 = expf(c2 - m);
  float inv = 1.f / (e0 + e1 + e2);
  float a_push = e0 * inv, a_pop = e1 * inv, a_noop = e2 * inv;

  int b = blockIdx.x;
  if (b >= 2048) {
    int r = b - 2048;
    float up = (r == 0) ? tanhf(ws[WS_SDOT + t]) : stack[(r - 1) * SW + t];
    float down = (r == SD - 1) ? 0.f : stack[(r + 1) * SW + t];
    out[4196 + r * SW + t] = a_noop * stack[r * SW + t] + a_push * up + a_pop * down;
    return;
  }
  __shared__ float st[SW];
  __shared__ float gred[3];
  st[t] = a_noop * stack[t] + a_push * tanhf(ws[WS_SDOT + t]) + a_pop * stack[SW + t];
  __syncthreads();
  int wv = t >> 6, lane = t & 63;
  int j = b;
  if (wv < 3) {
    const float4* w4 = (const float4*)(Wih0 + (size_t)(wv * H + j) * RIN + H);
    const float4* s4 = (const float4*)st;
    float4 a = w4[lane];
    float4 xv = s4[lane];
    float acc = a.x * xv.x + a.y * xv.y + a.z * xv.z + a.w * xv.w;
    acc = wave_reduce(acc);
    if (lane == 0) gred[wv] = acc;
  }
  __syncthreads();
  if (t == 0) {
    float gr = ws[WS_GI0 + j] + gred[0] + ws[WS_GH0 + j];
    float gz = ws[WS_GI0 + H + j] + gred[1] + ws[WS_GH0 + H + j];
    float r = sigmoidf(gr);
    float z = sigmoidf(gz);
    float n = tanhf(ws[WS_GI0 + 2 * H + j] + gred[2] + r * ws[WS_GH0 + 2 * H + j]);
    out[100 + j] = (1.f - z) * n + z * hidden[j];
  }
}

// K3: GRU layer1, fused matvec + combine. One j per block, 3 waves (192 thr).
__global__ __launch_bounds__(192)
void k3_gru1(const float* __restrict__ hidden,
             const float* __restrict__ Wih1, const float* __restrict__ bih1,
             const float* __restrict__ ws,
             float* out) {
  int j = blockIdx.x;
  int t = threadIdx.x, wv = t >> 6, lane = t & 63;
  const float* h0 = out + 100;  // written by k2
  __shared__ float gred[3];
  int row = wv * H + j;
  float d = wave_reduce(dot2048_part(Wih1 + (size_t)row * H, h0));
  if (lane == 0) gred[wv] = d + bih1[row];
  __syncthreads();
  if (t == 0) {
    float r = sigmoidf(gred[0] + ws[WS_GH1 + j]);
    float z = sigmoidf(gred[1] + ws[WS_GH1 + H + j]);
    float n = tanhf(gred[2] + r * ws[WS_GH1 + 2 * H + j]);
    out[100 + H + j] = (1.f - z) * n + z * hidden[H + j];
  }
}

// K4: logits = Wd @ h1 + bd. wave-per-row, 100 rows.
__global__ __launch_bounds__(256)
void k4_logits(const float* __restrict__ Wd, const float* __restrict__ bd,
               float* out) {
  int w = blockIdx.x * 4 + (threadIdx.x >> 6);
  int lane = threadIdx.x & 63;
  if (w >= 100) return;
  const float* h1 = out + 100 + H;  // written by k3
  float d = wave_reduce(dot2048_part(Wd + (size_t)w * H, h1));
  if (lane == 0) out[w] = d + bd[w];
}

extern "C" void kernel_launch(void* const* d_in, const int* in_sizes, int n_in,
                              void* d_out, int out_size, void* d_ws, size_t ws_size,
                              hipStream_t stream) {
  const int*   inp    = (const int*)d_in[0];
  const float* hidden = (const float*)d_in[1];
  const float* stack  = (const float*)d_in[2];
  const float* emb    = (const float*)d_in[3];
  const float* Wc     = (const float*)d_in[4];
  const float* bc     = (const float*)d_in[5];
  const float* Ws     = (const float*)d_in[6];
  const float* bs     = (const float*)d_in[7];
  const float* Wih0   = (const float*)d_in[8];
  const float* Whh0   = (const float*)d_in[9];
  const float* bih0   = (const float*)d_in[10];
  const float* bhh0   = (const float*)d_in[11];
  const float* Wih1   = (const float*)d_in[12];
  const float* Whh1   = (const float*)d_in[13];
  const float* bih1   = (const float*)d_in[14];
  const float* bhh1   = (const float*)d_in[15];
  const float* Wd     = (const float*)d_in[16];
  const float* bd     = (const float*)d_in[17];
  float* ws  = (float*)d_ws;
  float* out = (float*)d_out;

  k1_matvecs<<<4673, 256, 0, stream>>>(hidden, inp, emb, Wc, bc, Ws, bs,
                                       Wih0, bih0, Whh0, bhh0, Whh1, bhh1, ws);
  k2_stack_gru0<<<2248, 256, 0, stream>>>(stack, hidden, Wih0, ws, out);
  k3_gru1<<<2048, 192, 0, stream>>>(hidden, Wih1, bih1, ws, out);
  k4_logits<<<25, 256, 0, stream>>>(Wd, bd, out);
}